// Round 1
// baseline (3442.142 us; speedup 1.0000x reference)
//
#include <hip/hip_runtime.h>

#define D 128
#define DE 16
#define HD 128
#define MSG_IN 273
#define MSG_PAD 276   // multiple of 4 (b128 align), 276%32=20 -> rows spread over banks
#define HID_PAD 132   // 132%32=4 -> rows spread over banks
#define EB 32
#define NB 32
#define NT 256

// ---------------- edge kernel: msg MLP + atomic scatter-sum ----------------
__global__ __launch_bounds__(NT, 2) void edge_kernel(
    const float* __restrict__ f, const float* __restrict__ x,
    const float* __restrict__ w, const int* __restrict__ src,
    const int* __restrict__ dst,
    const float* __restrict__ Wm1, const float* __restrict__ bm1,
    const float* __restrict__ Wm2, const float* __restrict__ bm2,
    float* msum, int E)
{
    __shared__ __align__(16) float msg[EB][MSG_PAD];
    __shared__ __align__(16) float hid[EB][HID_PAD];
    __shared__ int s_src[EB], s_dst[EB];

    const int t  = threadIdx.x;
    const int e0 = blockIdx.x * EB;
    const int ne = min(EB, E - e0);

    if (t < ne) { s_src[t] = src[e0 + t]; s_dst[t] = dst[e0 + t]; }
    __syncthreads();

    // stage f[src] (cols 0..127) and f[dst] (cols 128..255)
    {
        const int half = t >> 7;     // 0: src-half, 1: dst-half
        const int tt   = t & 127;
        for (int e = 0; e < ne; ++e) {
            int node = half ? s_dst[e] : s_src[e];
            msg[e][half * D + tt] = f[(size_t)node * D + tt];
        }
    }
    // stage edge features w (cols 256..271)
    for (int idx = t; idx < EB * DE; idx += NT) {
        int e = idx >> 4, k = idx & 15;
        if (e < ne) msg[e][2 * D + k] = w[(size_t)(e0 + e) * DE + k];
    }
    // squared distance (col 272)
    if (t < ne) {
        int s = s_src[t], dd = s_dst[t];
        float dx = x[s*3+0] - x[dd*3+0];
        float dy = x[s*3+1] - x[dd*3+1];
        float dz = x[s*3+2] - x[dd*3+2];
        msg[t][2*D + DE] = dx*dx + dy*dy + dz*dz;
    }
    __syncthreads();

    const int tc  = t & 15;        // 16 col-groups of 8
    const int te2 = (t >> 4) * 2;  // 16 edge-groups of 2
    const int c0  = tc * 8;

    // ---- layer 1: [32,273] @ [273,128] + b, relu ----
    float a1[2][8];
    #pragma unroll
    for (int c = 0; c < 8; ++c) {
        float bv = bm1[c0 + c];
        a1[0][c] = bv; a1[1][c] = bv;
    }
    for (int i = 0; i < 272; i += 4) {
        float m0[4], m1[4];
        *(float4*)m0 = *(const float4*)&msg[te2][i];
        *(float4*)m1 = *(const float4*)&msg[te2 + 1][i];
        #pragma unroll
        for (int r = 0; r < 4; ++r) {
            float wr[8];
            *(float4*)&wr[0] = *(const float4*)(Wm1 + (size_t)(i + r) * HD + c0);
            *(float4*)&wr[4] = *(const float4*)(Wm1 + (size_t)(i + r) * HD + c0 + 4);
            #pragma unroll
            for (int c = 0; c < 8; ++c) {
                a1[0][c] += m0[r] * wr[c];
                a1[1][c] += m1[r] * wr[c];
            }
        }
    }
    {   // tail row i = 272 (sqd column)
        float m0 = msg[te2][272], m1 = msg[te2 + 1][272];
        float wr[8];
        *(float4*)&wr[0] = *(const float4*)(Wm1 + (size_t)272 * HD + c0);
        *(float4*)&wr[4] = *(const float4*)(Wm1 + (size_t)272 * HD + c0 + 4);
        #pragma unroll
        for (int c = 0; c < 8; ++c) {
            a1[0][c] += m0 * wr[c];
            a1[1][c] += m1 * wr[c];
        }
    }
    #pragma unroll
    for (int j = 0; j < 2; ++j) {
        float v[8];
        #pragma unroll
        for (int c = 0; c < 8; ++c) v[c] = fmaxf(a1[j][c], 0.f);
        *(float4*)&hid[te2 + j][c0]     = *(float4*)&v[0];
        *(float4*)&hid[te2 + j][c0 + 4] = *(float4*)&v[4];
    }
    __syncthreads();

    // ---- layer 2: [32,128] @ [128,128] + b, atomic scatter ----
    float a2[2][8];
    #pragma unroll
    for (int c = 0; c < 8; ++c) {
        float bv = bm2[c0 + c];
        a2[0][c] = bv; a2[1][c] = bv;
    }
    for (int h = 0; h < HD; h += 4) {
        float m0[4], m1[4];
        *(float4*)m0 = *(const float4*)&hid[te2][h];
        *(float4*)m1 = *(const float4*)&hid[te2 + 1][h];
        #pragma unroll
        for (int r = 0; r < 4; ++r) {
            float wr[8];
            *(float4*)&wr[0] = *(const float4*)(Wm2 + (size_t)(h + r) * D + c0);
            *(float4*)&wr[4] = *(const float4*)(Wm2 + (size_t)(h + r) * D + c0 + 4);
            #pragma unroll
            for (int c = 0; c < 8; ++c) {
                a2[0][c] += m0[r] * wr[c];
                a2[1][c] += m1[r] * wr[c];
            }
        }
    }
    #pragma unroll
    for (int j = 0; j < 2; ++j) {
        int e = te2 + j;
        if (e < ne) {
            float* p = msum + (size_t)s_dst[e] * D + c0;
            #pragma unroll
            for (int c = 0; c < 8; ++c) atomicAdd(p + c, a2[j][c]);
        }
    }
}

// ---------------- node kernel: update MLP ----------------
__global__ __launch_bounds__(NT, 2) void node_kernel(
    const float* __restrict__ f, const float* msum,
    const float* __restrict__ Wu1, const float* __restrict__ bu1,
    const float* __restrict__ Wu2, const float* __restrict__ bu2,
    float* out, int Nn)
{
    __shared__ __align__(16) float hin[NB][HID_PAD];
    __shared__ __align__(16) float hid[NB][HID_PAD];
    const int t  = threadIdx.x;
    const int n0 = blockIdx.x * NB;
    const int nn = min(NB, Nn - n0);

    {
        const int half = t >> 7, tt = t & 127;
        for (int e = half; e < nn; e += 2) {
            size_t off = (size_t)(n0 + e) * D + tt;
            hin[e][tt] = msum[off] + f[off];
        }
    }
    __syncthreads();

    const int tc  = t & 15;
    const int te2 = (t >> 4) * 2;
    const int c0  = tc * 8;

    float a1[2][8];
    #pragma unroll
    for (int c = 0; c < 8; ++c) {
        float bv = bu1[c0 + c];
        a1[0][c] = bv; a1[1][c] = bv;
    }
    for (int i = 0; i < D; i += 4) {
        float m0[4], m1[4];
        *(float4*)m0 = *(const float4*)&hin[te2][i];
        *(float4*)m1 = *(const float4*)&hin[te2 + 1][i];
        #pragma unroll
        for (int r = 0; r < 4; ++r) {
            float wr[8];
            *(float4*)&wr[0] = *(const float4*)(Wu1 + (size_t)(i + r) * HD + c0);
            *(float4*)&wr[4] = *(const float4*)(Wu1 + (size_t)(i + r) * HD + c0 + 4);
            #pragma unroll
            for (int c = 0; c < 8; ++c) {
                a1[0][c] += m0[r] * wr[c];
                a1[1][c] += m1[r] * wr[c];
            }
        }
    }
    #pragma unroll
    for (int j = 0; j < 2; ++j) {
        float v[8];
        #pragma unroll
        for (int c = 0; c < 8; ++c) v[c] = fmaxf(a1[j][c], 0.f);
        *(float4*)&hid[te2 + j][c0]     = *(float4*)&v[0];
        *(float4*)&hid[te2 + j][c0 + 4] = *(float4*)&v[4];
    }
    __syncthreads();

    float a2[2][8];
    #pragma unroll
    for (int c = 0; c < 8; ++c) {
        float bv = bu2[c0 + c];
        a2[0][c] = bv; a2[1][c] = bv;
    }
    for (int h = 0; h < HD; h += 4) {
        float m0[4], m1[4];
        *(float4*)m0 = *(const float4*)&hid[te2][h];
        *(float4*)m1 = *(const float4*)&hid[te2 + 1][h];
        #pragma unroll
        for (int r = 0; r < 4; ++r) {
            float wr[8];
            *(float4*)&wr[0] = *(const float4*)(Wu2 + (size_t)(h + r) * D + c0);
            *(float4*)&wr[4] = *(const float4*)(Wu2 + (size_t)(h + r) * D + c0 + 4);
            #pragma unroll
            for (int c = 0; c < 8; ++c) {
                a2[0][c] += m0[r] * wr[c];
                a2[1][c] += m1[r] * wr[c];
            }
        }
    }
    #pragma unroll
    for (int j = 0; j < 2; ++j) {
        int e = te2 + j;
        int gn = n0 + e;
        if (e < nn) {
            *(float4*)(out + (size_t)gn * D + c0)     = *(float4*)&a2[j][0];
            *(float4*)(out + (size_t)gn * D + c0 + 4) = *(float4*)&a2[j][4];
        }
    }
}

extern "C" void kernel_launch(void* const* d_in, const int* in_sizes, int n_in,
                              void* d_out, int out_size, void* d_ws, size_t ws_size,
                              hipStream_t stream) {
    const float* f   = (const float*)d_in[0];
    const float* x   = (const float*)d_in[1];
    const float* w   = (const float*)d_in[2];
    const int*   src = (const int*)d_in[3];
    const int*   dst = (const int*)d_in[4];
    const float* Wm1 = (const float*)d_in[5];
    const float* bm1 = (const float*)d_in[6];
    const float* Wm2 = (const float*)d_in[7];
    const float* bm2 = (const float*)d_in[8];
    const float* Wu1 = (const float*)d_in[9];
    const float* bu1 = (const float*)d_in[10];
    const float* Wu2 = (const float*)d_in[11];
    const float* bu2 = (const float*)d_in[12];

    const int Nn = in_sizes[0] / D;
    const int E  = in_sizes[3];

    const size_t msum_bytes = (size_t)Nn * D * sizeof(float);
    // Prefer workspace; fall back to d_out (safe: node_kernel reads its own
    // rows before overwriting them, no cross-block overlap).
    float* msum = (ws_size >= msum_bytes) ? (float*)d_ws : (float*)d_out;

    hipMemsetAsync(msum, 0, msum_bytes, stream);

    edge_kernel<<<dim3((E + EB - 1) / EB), dim3(NT), 0, stream>>>(
        f, x, w, src, dst, Wm1, bm1, Wm2, bm2, msum, E);
    node_kernel<<<dim3((Nn + NB - 1) / NB), dim3(NT), 0, stream>>>(
        f, msum, Wu1, bu1, Wu2, bu2, (float*)d_out, Nn);
}

// Round 2
// 607.430 us; speedup vs baseline: 5.6667x; 5.6667x over previous
//
#include <hip/hip_runtime.h>

#define D 128
#define HD 128
#define DE 16
#define MSG_IN 273
#define EB 64        // edges per block (mfma path)
#define NT 256
#define KP1 288      // padded msg K = 9 chunks of 32
#define NCH1 9
#define NCH2 4
#define NB 32
#define MSG_PAD 276  // fp32 fallback kernel
#define HID_PAD 132

typedef __attribute__((ext_vector_type(8))) short short8v;
typedef __attribute__((ext_vector_type(4))) float f32x4;
typedef unsigned short ushort_t;

__device__ __forceinline__ unsigned short f2bf(float v) {
    unsigned int u = __builtin_bit_cast(unsigned int, v);
    u += 0x7fffu + ((u >> 16) & 1u);
    return (unsigned short)(u >> 16);
}

// ---------------- weight repack: fp32 [K][N] -> bf16 transposed [N][Kpad] ----------------
__global__ void repack_kernel(const float* __restrict__ Wm1, const float* __restrict__ Wm2,
                              ushort_t* __restrict__ W1p, ushort_t* __restrict__ W2p) {
    int idx = blockIdx.x * 256 + threadIdx.x;
    const int n1 = 128 * KP1;
    if (idx < n1) {
        int n = idx / KP1, k = idx % KP1;
        float v = (k < MSG_IN) ? Wm1[(size_t)k * HD + n] : 0.f;
        W1p[idx] = f2bf(v);
    } else {
        int i2 = idx - n1;
        if (i2 < HD * D) {
            int n = i2 / HD, k = i2 % HD;
            W2p[i2] = f2bf(Wm2[(size_t)k * D + n]);
        }
    }
}

// ---------------- edge kernel (MFMA bf16): msg MLP + atomic scatter-sum ----------------
__global__ __launch_bounds__(NT, 3) void edge_mfma_kernel(
    const float* __restrict__ f, const float* __restrict__ x,
    const float* __restrict__ w, const int* __restrict__ src,
    const int* __restrict__ dst,
    const ushort_t* __restrict__ W1p, const float* __restrict__ bm1,
    const ushort_t* __restrict__ W2p, const float* __restrict__ bm2,
    float* msum, int E)
{
    // chunked layouts: [chunk][edge][32 k] bf16 -> row stride 64B, balanced banks
    __shared__ __align__(16) ushort_t msg_c[NCH1 * EB * 32];  // 36,864 B
    __shared__ __align__(16) ushort_t hid_c[NCH2 * EB * 32];  // 16,384 B

    const int t  = threadIdx.x;
    const int e0 = blockIdx.x * EB;

    // ---- stage f[src] (k 0..127) | f[dst] (k 128..255) as bf16 ----
    {
        const int e = t >> 2, q = t & 3;
        const int ge = e0 + e;
        const bool ok = ge < E;
        const int ns = ok ? src[ge] : 0;
        const int nd = ok ? dst[ge] : 0;
        #pragma unroll
        for (int i = 0; i < 8; ++i) {
            const int k0 = i * 32 + q * 8;           // chunk = i
            union { unsigned short us[8]; short8v v; } pk;
            if (ok) {
                const float* base = (k0 < D) ? (f + (size_t)ns * D + k0)
                                             : (f + (size_t)nd * D + (k0 - D));
                float4 v0 = *(const float4*)base;
                float4 v1 = *(const float4*)(base + 4);
                pk.us[0] = f2bf(v0.x); pk.us[1] = f2bf(v0.y);
                pk.us[2] = f2bf(v0.z); pk.us[3] = f2bf(v0.w);
                pk.us[4] = f2bf(v1.x); pk.us[5] = f2bf(v1.y);
                pk.us[6] = f2bf(v1.z); pk.us[7] = f2bf(v1.w);
            } else {
                #pragma unroll
                for (int j = 0; j < 8; ++j) pk.us[j] = 0;
            }
            *(short8v*)&msg_c[(i * EB + e) * 32 + q * 8] = pk.v;
        }
    }
    // ---- chunk 8: edge feats (k 256..271), sqd (272), zero pad (273..287) ----
    if (t < EB) {
        const int ge = e0 + t;
        const bool ok = ge < E;
        __align__(16) unsigned short row[32];
        #pragma unroll
        for (int j = 0; j < 32; ++j) row[j] = 0;
        if (ok) {
            #pragma unroll
            for (int j = 0; j < DE; ++j) row[j] = f2bf(w[(size_t)ge * DE + j]);
            const int ns = src[ge], nd = dst[ge];
            float dx = x[ns*3+0] - x[nd*3+0];
            float dy = x[ns*3+1] - x[nd*3+1];
            float dz = x[ns*3+2] - x[nd*3+2];
            row[DE] = f2bf(dx*dx + dy*dy + dz*dz);
        }
        #pragma unroll
        for (int ii = 0; ii < 4; ++ii)
            *(short8v*)&msg_c[(8 * EB + t) * 32 + ii * 8] = *(short8v*)&row[ii * 8];
    }
    __syncthreads();

    const int lane = t & 63;
    const int wv   = t >> 6;        // wave 0..3 owns edges [16wv, 16wv+16)
    const int col  = lane & 15;     // output col within 16-tile / A row
    const int g    = lane >> 4;     // k-group
    const int erow = wv * 16 + col;

    // ---- layer 1: [16,288] x [288,128] per wave ----
    f32x4 acc[8];
    #pragma unroll
    for (int ct = 0; ct < 8; ++ct) {
        float bv = bm1[ct * 16 + col];
        acc[ct] = (f32x4){bv, bv, bv, bv};
    }
    for (int c = 0; c < NCH1; ++c) {
        short8v a = *(const short8v*)&msg_c[(c * EB + erow) * 32 + g * 8];
        #pragma unroll
        for (int ct = 0; ct < 8; ++ct) {
            short8v b = *(const short8v*)&W1p[(size_t)(ct * 16 + col) * KP1 + c * 32 + g * 8];
            acc[ct] = __builtin_amdgcn_mfma_f32_16x16x32_bf16(a, b, acc[ct], 0, 0, 0);
        }
    }
    // relu -> bf16 hid (wave-local rows: no barrier needed)
    #pragma unroll
    for (int ct = 0; ct < 8; ++ct) {
        const int h  = ct * 16 + col;
        const int hc = h >> 5, hi = h & 31;
        #pragma unroll
        for (int r = 0; r < 4; ++r) {
            const int e = wv * 16 + g * 4 + r;
            hid_c[(hc * EB + e) * 32 + hi] = f2bf(fmaxf(acc[ct][r], 0.f));
        }
    }

    // ---- layer 2: [16,128] x [128,128] per wave ----
    f32x4 acc2[8];
    #pragma unroll
    for (int ct = 0; ct < 8; ++ct) {
        float bv = bm2[ct * 16 + col];
        acc2[ct] = (f32x4){bv, bv, bv, bv};
    }
    for (int c = 0; c < NCH2; ++c) {
        short8v a = *(const short8v*)&hid_c[(c * EB + erow) * 32 + g * 8];
        #pragma unroll
        for (int ct = 0; ct < 8; ++ct) {
            short8v b = *(const short8v*)&W2p[(size_t)(ct * 16 + col) * HD + c * 32 + g * 8];
            acc2[ct] = __builtin_amdgcn_mfma_f32_16x16x32_bf16(a, b, acc2[ct], 0, 0, 0);
        }
    }

    // ---- atomic scatter to msum[dst] ----
    #pragma unroll
    for (int r = 0; r < 4; ++r) {
        const int el = wv * 16 + g * 4 + r;
        const int ge = e0 + el;
        if (ge < E) {
            const int dg = dst[ge];
            float* p = msum + (size_t)dg * D + col;
            #pragma unroll
            for (int ct = 0; ct < 8; ++ct)
                atomicAdd(p + ct * 16, acc2[ct][r]);
        }
    }
}

// ---------------- fp32 fallback edge kernel (only if ws too small to repack) ----------------
__global__ __launch_bounds__(NT, 2) void edge_kernel_f32(
    const float* __restrict__ f, const float* __restrict__ x,
    const float* __restrict__ w, const int* __restrict__ src,
    const int* __restrict__ dst,
    const float* __restrict__ Wm1, const float* __restrict__ bm1,
    const float* __restrict__ Wm2, const float* __restrict__ bm2,
    float* msum, int E)
{
    __shared__ __align__(16) float msg[32][MSG_PAD];
    __shared__ __align__(16) float hid[32][HID_PAD];
    __shared__ int s_src[32], s_dst[32];

    const int t  = threadIdx.x;
    const int e0 = blockIdx.x * 32;
    const int ne = min(32, E - e0);

    if (t < ne) { s_src[t] = src[e0 + t]; s_dst[t] = dst[e0 + t]; }
    __syncthreads();
    {
        const int half = t >> 7, tt = t & 127;
        for (int e = 0; e < ne; ++e) {
            int node = half ? s_dst[e] : s_src[e];
            msg[e][half * D + tt] = f[(size_t)node * D + tt];
        }
    }
    for (int idx = t; idx < 32 * DE; idx += NT) {
        int e = idx >> 4, k = idx & 15;
        if (e < ne) msg[e][2 * D + k] = w[(size_t)(e0 + e) * DE + k];
    }
    if (t < ne) {
        int s = s_src[t], dd = s_dst[t];
        float dx = x[s*3+0]-x[dd*3+0], dy = x[s*3+1]-x[dd*3+1], dz = x[s*3+2]-x[dd*3+2];
        msg[t][2*D + DE] = dx*dx + dy*dy + dz*dz;
    }
    __syncthreads();

    const int tc = t & 15, te2 = (t >> 4) * 2, c0 = tc * 8;
    float a1[2][8];
    #pragma unroll
    for (int c = 0; c < 8; ++c) { float bv = bm1[c0 + c]; a1[0][c] = bv; a1[1][c] = bv; }
    for (int i = 0; i < 272; i += 4) {
        float m0[4], m1[4];
        *(float4*)m0 = *(const float4*)&msg[te2][i];
        *(float4*)m1 = *(const float4*)&msg[te2 + 1][i];
        #pragma unroll
        for (int r = 0; r < 4; ++r) {
            float wr[8];
            *(float4*)&wr[0] = *(const float4*)(Wm1 + (size_t)(i + r) * HD + c0);
            *(float4*)&wr[4] = *(const float4*)(Wm1 + (size_t)(i + r) * HD + c0 + 4);
            #pragma unroll
            for (int c = 0; c < 8; ++c) { a1[0][c] += m0[r]*wr[c]; a1[1][c] += m1[r]*wr[c]; }
        }
    }
    {
        float m0 = msg[te2][272], m1 = msg[te2 + 1][272];
        float wr[8];
        *(float4*)&wr[0] = *(const float4*)(Wm1 + (size_t)272 * HD + c0);
        *(float4*)&wr[4] = *(const float4*)(Wm1 + (size_t)272 * HD + c0 + 4);
        #pragma unroll
        for (int c = 0; c < 8; ++c) { a1[0][c] += m0*wr[c]; a1[1][c] += m1*wr[c]; }
    }
    #pragma unroll
    for (int j = 0; j < 2; ++j) {
        float v[8];
        #pragma unroll
        for (int c = 0; c < 8; ++c) v[c] = fmaxf(a1[j][c], 0.f);
        *(float4*)&hid[te2 + j][c0] = *(float4*)&v[0];
        *(float4*)&hid[te2 + j][c0 + 4] = *(float4*)&v[4];
    }
    __syncthreads();
    float a2[2][8];
    #pragma unroll
    for (int c = 0; c < 8; ++c) { float bv = bm2[c0 + c]; a2[0][c] = bv; a2[1][c] = bv; }
    for (int h = 0; h < HD; h += 4) {
        float m0[4], m1[4];
        *(float4*)m0 = *(const float4*)&hid[te2][h];
        *(float4*)m1 = *(const float4*)&hid[te2 + 1][h];
        #pragma unroll
        for (int r = 0; r < 4; ++r) {
            float wr[8];
            *(float4*)&wr[0] = *(const float4*)(Wm2 + (size_t)(h + r) * D + c0);
            *(float4*)&wr[4] = *(const float4*)(Wm2 + (size_t)(h + r) * D + c0 + 4);
            #pragma unroll
            for (int c = 0; c < 8; ++c) { a2[0][c] += m0[r]*wr[c]; a2[1][c] += m1[r]*wr[c]; }
        }
    }
    #pragma unroll
    for (int j = 0; j < 2; ++j) {
        int e = te2 + j;
        if (e < ne) {
            float* p = msum + (size_t)s_dst[e] * D + c0;
            #pragma unroll
            for (int c = 0; c < 8; ++c) atomicAdd(p + c, a2[j][c]);
        }
    }
}

// ---------------- node kernel: update MLP (fp32) ----------------
__global__ __launch_bounds__(NT, 2) void node_kernel(
    const float* __restrict__ f, const float* msum,
    const float* __restrict__ Wu1, const float* __restrict__ bu1,
    const float* __restrict__ Wu2, const float* __restrict__ bu2,
    float* out, int Nn)
{
    __shared__ __align__(16) float hin[NB][HID_PAD];
    __shared__ __align__(16) float hid[NB][HID_PAD];
    const int t  = threadIdx.x;
    const int n0 = blockIdx.x * NB;
    const int nn = min(NB, Nn - n0);

    {
        const int half = t >> 7, tt = t & 127;
        for (int e = half; e < nn; e += 2) {
            size_t off = (size_t)(n0 + e) * D + tt;
            hin[e][tt] = msum[off] + f[off];
        }
    }
    __syncthreads();

    const int tc = t & 15, te2 = (t >> 4) * 2, c0 = tc * 8;
    float a1[2][8];
    #pragma unroll
    for (int c = 0; c < 8; ++c) { float bv = bu1[c0 + c]; a1[0][c] = bv; a1[1][c] = bv; }
    for (int i = 0; i < D; i += 4) {
        float m0[4], m1[4];
        *(float4*)m0 = *(const float4*)&hin[te2][i];
        *(float4*)m1 = *(const float4*)&hin[te2 + 1][i];
        #pragma unroll
        for (int r = 0; r < 4; ++r) {
            float wr[8];
            *(float4*)&wr[0] = *(const float4*)(Wu1 + (size_t)(i + r) * HD + c0);
            *(float4*)&wr[4] = *(const float4*)(Wu1 + (size_t)(i + r) * HD + c0 + 4);
            #pragma unroll
            for (int c = 0; c < 8; ++c) { a1[0][c] += m0[r]*wr[c]; a1[1][c] += m1[r]*wr[c]; }
        }
    }
    #pragma unroll
    for (int j = 0; j < 2; ++j) {
        float v[8];
        #pragma unroll
        for (int c = 0; c < 8; ++c) v[c] = fmaxf(a1[j][c], 0.f);
        *(float4*)&hid[te2 + j][c0] = *(float4*)&v[0];
        *(float4*)&hid[te2 + j][c0 + 4] = *(float4*)&v[4];
    }
    __syncthreads();
    float a2[2][8];
    #pragma unroll
    for (int c = 0; c < 8; ++c) { float bv = bu2[c0 + c]; a2[0][c] = bv; a2[1][c] = bv; }
    for (int h = 0; h < HD; h += 4) {
        float m0[4], m1[4];
        *(float4*)m0 = *(const float4*)&hid[te2][h];
        *(float4*)m1 = *(const float4*)&hid[te2 + 1][h];
        #pragma unroll
        for (int r = 0; r < 4; ++r) {
            float wr[8];
            *(float4*)&wr[0] = *(const float4*)(Wu2 + (size_t)(h + r) * D + c0);
            *(float4*)&wr[4] = *(const float4*)(Wu2 + (size_t)(h + r) * D + c0 + 4);
            #pragma unroll
            for (int c = 0; c < 8; ++c) { a2[0][c] += m0[r]*wr[c]; a2[1][c] += m1[r]*wr[c]; }
        }
    }
    #pragma unroll
    for (int j = 0; j < 2; ++j) {
        int e = te2 + j, gn = n0 + e;
        if (e < nn) {
            *(float4*)(out + (size_t)gn * D + c0) = *(float4*)&a2[j][0];
            *(float4*)(out + (size_t)gn * D + c0 + 4) = *(float4*)&a2[j][4];
        }
    }
}

extern "C" void kernel_launch(void* const* d_in, const int* in_sizes, int n_in,
                              void* d_out, int out_size, void* d_ws, size_t ws_size,
                              hipStream_t stream) {
    const float* f   = (const float*)d_in[0];
    const float* x   = (const float*)d_in[1];
    const float* w   = (const float*)d_in[2];
    const int*   src = (const int*)d_in[3];
    const int*   dst = (const int*)d_in[4];
    const float* Wm1 = (const float*)d_in[5];
    const float* bm1 = (const float*)d_in[6];
    const float* Wm2 = (const float*)d_in[7];
    const float* bm2 = (const float*)d_in[8];
    const float* Wu1 = (const float*)d_in[9];
    const float* bu1 = (const float*)d_in[10];
    const float* Wu2 = (const float*)d_in[11];
    const float* bu2 = (const float*)d_in[12];

    const int Nn = in_sizes[0] / D;
    const int E  = in_sizes[3];

    const size_t msum_bytes = (size_t)Nn * D * sizeof(float);
    const size_t wbytes = (size_t)(128 * KP1 + HD * D) * sizeof(ushort_t); // 106,496 B
    const size_t woff   = (wbytes + 511) & ~(size_t)511;

    float* msum;
    ushort_t* W1p = nullptr;
    bool use_mfma;
    if (ws_size >= woff + msum_bytes) {
        W1p = (ushort_t*)d_ws;
        msum = (float*)((char*)d_ws + woff);
        use_mfma = true;
    } else if (ws_size >= wbytes) {
        W1p = (ushort_t*)d_ws;
        msum = (float*)d_out;   // safe: node_kernel reads its rows before writing
        use_mfma = true;
    } else {
        use_mfma = false;
        msum = (ws_size >= msum_bytes) ? (float*)d_ws : (float*)d_out;
    }

    hipMemsetAsync(msum, 0, msum_bytes, stream);

    if (use_mfma) {
        ushort_t* W2p = W1p + 128 * KP1;
        const int rp_elems = 128 * KP1 + HD * D;
        repack_kernel<<<dim3((rp_elems + 255) / 256), dim3(256), 0, stream>>>(Wm1, Wm2, W1p, W2p);
        edge_mfma_kernel<<<dim3((E + EB - 1) / EB), dim3(NT), 0, stream>>>(
            f, x, w, src, dst, W1p, bm1, W2p, bm2, msum, E);
    } else {
        edge_kernel_f32<<<dim3((E + 31) / 32), dim3(NT), 0, stream>>>(
            f, x, w, src, dst, Wm1, bm1, Wm2, bm2, msum, E);
    }
    node_kernel<<<dim3((Nn + NB - 1) / NB), dim3(NT), 0, stream>>>(
        f, msum, Wu1, bu1, Wu2, bu2, (float*)d_out, Nn);
}